// Round 2
// baseline (208.745 us; speedup 1.0000x reference)
//
#include <hip/hip_runtime.h>

#define ALPHA 0.2f

__device__ __forceinline__ float bf2f(unsigned short u) {
    return __uint_as_float(((unsigned int)u) << 16);
}
__device__ __forceinline__ unsigned short f2bf(float f) {
    unsigned int x = __float_as_uint(f);
    unsigned int r = (x + 0x7fffu + ((x >> 16) & 1u)) >> 16;   // round-nearest-even
    return (unsigned short)r;
}

// ---------------------------------------------------------------------------
// Kernel 0: detect on-device whether float inputs are fp32 or bf16, and
// whether edge_index is int64 or int32. Deterministic, runs every call.
// flags[0]: 1 = floats are fp32, 0 = bf16. flags[1]: 1 = edges int64, 0 = int32.
// ---------------------------------------------------------------------------
__global__ __launch_bounds__(256) void detect_types(const unsigned int* __restrict__ xw,
                                                    const int* __restrict__ ei32,
                                                    int* __restrict__ flags) {
    __shared__ int cnt[2];
    if (threadIdx.x == 0) { cnt[0] = 0; cnt[1] = 0; }
    __syncthreads();
    int c0 = 0, c1 = 0;
    int t = threadIdx.x;
    for (int i = 0; i < 8; i++) {
        int k = t * 8 + i;                       // 2048 samples
        unsigned int u = xw[k];
        unsigned int e = (u >> 7) & 0xffu;       // exponent field of low u16 as bf16
        if (e >= 0x58u && e <= 0x90u) c0++;      // plausible bf16(N(0,1)) exponent
        if (ei32[2 * k + 1] != 0) c1++;          // int64 high halves are all zero
    }
    atomicAdd(&cnt[0], c0);
    atomicAdd(&cnt[1], c1);
    __syncthreads();
    if (threadIdx.x == 0) {
        flags[0] = (cnt[0] < 1200) ? 1 : 0;      // bf16 data => ~2048; fp32 => ~450
        flags[1] = (cnt[1] < 1000) ? 1 : 0;      // int32 data => ~2047; int64 => 0
    }
}

// ---------------------------------------------------------------------------
// Kernel 1: adjacency bitmask (dedups duplicate edges like reference bool adj).
// ---------------------------------------------------------------------------
__global__ __launch_bounds__(256) void build_adj(const int* __restrict__ ei, int E, int N,
                                                 unsigned long long* __restrict__ adj,
                                                 const int* __restrict__ flags) {
    int is64 = flags[1];
    int t = blockIdx.x * blockDim.x + threadIdx.x;
    int words = N >> 6;
    if (t < E) {
        int r = is64 ? ei[2 * t]       : ei[t];
        int c = is64 ? ei[2 * (E + t)] : ei[E + t];
        atomicOr(&adj[(size_t)r * words + (c >> 6)], 1ull << (c & 63));
    } else if (t < E + N) {
        int i = t - E;
        atomicOr(&adj[(size_t)i * words + (i >> 6)], 1ull << (i & 63));
    }
}

// ---------------------------------------------------------------------------
// Kernel 2: h[head] = x @ W[head]   (bf16 OR fp32 in, fp32 out)
// x: N x C, W: H x C x F, h: H x N x F (fp32)
// 64x64 output tile per block, BK=32, 256 threads, each computes 4x4.
// ---------------------------------------------------------------------------
#define BM 64
#define BN 64
#define BK 32
__global__ __launch_bounds__(256) void gemm_h(const void* __restrict__ x_raw,
                                              const void* __restrict__ W_raw,
                                              float* __restrict__ h,
                                              int N, int C, int Fdim,
                                              const int* __restrict__ flags) {
    int is32 = flags[0];
    int head = blockIdx.y;
    int row0 = blockIdx.x * BM;

    __shared__ float sx[BK][BM + 4];
    __shared__ float sw[BK][BN + 4];

    int tid = threadIdx.x;
    int tx = tid & 15;
    int ty = tid >> 4;
    float acc[4][4] = {};

    for (int k0 = 0; k0 < C; k0 += BK) {
        if (is32) {
            const float* xf = (const float*)x_raw;
            const float* Wf = (const float*)W_raw + (size_t)head * C * Fdim;
#pragma unroll
            for (int i = 0; i < 8; i++) {
                int flat = tid + i * 256;            // 0..2047
                int r = flat >> 5, k = flat & 31;
                sx[k][r] = xf[(size_t)(row0 + r) * C + k0 + k];
                int kk = flat >> 6, f = flat & 63;
                sw[kk][f] = Wf[(size_t)(k0 + kk) * Fdim + f];
            }
        } else {
            const unsigned short* xb = (const unsigned short*)x_raw;
            const unsigned short* Wb = (const unsigned short*)W_raw + (size_t)head * C * Fdim;
#pragma unroll
            for (int i = 0; i < 4; i++) {
                int flat2 = tid + i * 256;           // 0..1023 pairs
                int r = flat2 >> 4, k2 = flat2 & 15;
                unsigned int u = *(const unsigned int*)(xb + (size_t)(row0 + r) * C + k0 + k2 * 2);
                sx[k2 * 2 + 0][r] = bf2f((unsigned short)(u & 0xffff));
                sx[k2 * 2 + 1][r] = bf2f((unsigned short)(u >> 16));
                int kk = flat2 >> 5, f2 = flat2 & 31;
                unsigned int v = *(const unsigned int*)(Wb + (size_t)(k0 + kk) * Fdim + f2 * 2);
                sw[kk][f2 * 2 + 0] = bf2f((unsigned short)(v & 0xffff));
                sw[kk][f2 * 2 + 1] = bf2f((unsigned short)(v >> 16));
            }
        }
        __syncthreads();
#pragma unroll
        for (int k = 0; k < BK; k++) {
            float a0 = sx[k][ty * 4 + 0], a1 = sx[k][ty * 4 + 1];
            float a2 = sx[k][ty * 4 + 2], a3 = sx[k][ty * 4 + 3];
            float b0 = sw[k][tx * 4 + 0], b1 = sw[k][tx * 4 + 1];
            float b2 = sw[k][tx * 4 + 2], b3 = sw[k][tx * 4 + 3];
            acc[0][0] += a0 * b0; acc[0][1] += a0 * b1; acc[0][2] += a0 * b2; acc[0][3] += a0 * b3;
            acc[1][0] += a1 * b0; acc[1][1] += a1 * b1; acc[1][2] += a1 * b2; acc[1][3] += a1 * b3;
            acc[2][0] += a2 * b0; acc[2][1] += a2 * b1; acc[2][2] += a2 * b2; acc[2][3] += a2 * b3;
            acc[3][0] += a3 * b0; acc[3][1] += a3 * b1; acc[3][2] += a3 * b2; acc[3][3] += a3 * b3;
        }
        __syncthreads();
    }
#pragma unroll
    for (int i = 0; i < 4; i++) {
        float4 v = make_float4(acc[i][0], acc[i][1], acc[i][2], acc[i][3]);
        *(float4*)(h + ((size_t)head * N + row0 + ty * 4 + i) * Fdim + tx * 4) = v;
    }
}

// ---------------------------------------------------------------------------
// Kernel 3: s_src[h,n] = h[h,n,:] . a[h,0:F],  s_dst[h,n] = h[h,n,:] . a[h,F:2F]
// ---------------------------------------------------------------------------
__global__ __launch_bounds__(256) void calc_s(const float* __restrict__ h,
                                              const void* __restrict__ a_raw,
                                              float* __restrict__ s_src,
                                              float* __restrict__ s_dst,
                                              int N, int Fdim, int H,
                                              const int* __restrict__ flags) {
    int is32 = flags[0];
    int wid = threadIdx.x >> 6, lane = threadIdx.x & 63;
    int row = blockIdx.x * 4 + wid;
    if (row >= H * N) return;
    int hh = row / N;
    float v = h[(size_t)row * Fdim + lane];
    float a1, a2;
    if (is32) {
        const float* af = (const float*)a_raw;
        a1 = af[hh * 2 * Fdim + lane];
        a2 = af[hh * 2 * Fdim + Fdim + lane];
    } else {
        const unsigned short* ab = (const unsigned short*)a_raw;
        a1 = bf2f(ab[hh * 2 * Fdim + lane]);
        a2 = bf2f(ab[hh * 2 * Fdim + Fdim + lane]);
    }
    float s1 = v * a1, s2 = v * a2;
#pragma unroll
    for (int d = 32; d; d >>= 1) {
        s1 += __shfl_down(s1, d);
        s2 += __shfl_down(s2, d);
    }
    if (lane == 0) { s_src[row] = s1; s_dst[row] = s2; }
}

// ---------------------------------------------------------------------------
// Kernel 4: attention + aggregation. Block per node i.
// ---------------------------------------------------------------------------
__global__ __launch_bounds__(256) void attn(const float* __restrict__ h,
                                            const float* __restrict__ s_src,
                                            const float* __restrict__ s_dst,
                                            const unsigned long long* __restrict__ adj,
                                            float* __restrict__ out_pre,
                                            int N, int Fdim, int H) {
    __shared__ unsigned short nbrs[4096];
    __shared__ float sacc[4][64];
    __shared__ float sden[4];
    __shared__ float sred[8];
    __shared__ int s_cnt;

    int i = blockIdx.x;
    int tid = threadIdx.x;
    int lane = tid & 63, wid = tid >> 6;

    if (tid < 64) {
        unsigned long long word = adj[(size_t)i * 64 + tid];
        int cnt = __popcll(word);
        int incl = cnt;
#pragma unroll
        for (int d = 1; d < 64; d <<= 1) {
            int v = __shfl_up(incl, d);
            if (tid >= d) incl += v;
        }
        int off = incl - cnt;
        unsigned long long w = word;
        int base = tid * 64;
        while (w) {
            int b = __ffsll((unsigned long long)w) - 1;
            nbrs[off++] = (unsigned short)(base + b);
            w &= w - 1;
        }
        if (tid == 63) s_cnt = incl;
    }
    __syncthreads();
    int cnt = s_cnt;

    for (int hh = 0; hh < H; hh++) {
        float ssrc = s_src[hh * N + i];
        float m = -1e30f;
        for (int t = tid; t < cnt; t += 256) m = fmaxf(m, s_dst[hh * N + nbrs[t]]);
#pragma unroll
        for (int d = 32; d; d >>= 1) m = fmaxf(m, __shfl_down(m, d));
        if (lane == 0) sred[wid] = m;
        __syncthreads();
        float mdst = fmaxf(fmaxf(sred[0], sred[1]), fmaxf(sred[2], sred[3]));
        float pre = ssrc + mdst;
        float maxe = pre > 0.f ? pre : ALPHA * pre;

        float acc = 0.f, den = 0.f;
        const float* hbase = h + (size_t)hh * N * Fdim;
        for (int t = wid; t < cnt; t += 4) {
            int j = nbrs[t];
            float e = ssrc + s_dst[hh * N + j];
            e = e > 0.f ? e : ALPHA * e;
            float w = __expf(e - maxe);
            den += w;
            acc += w * hbase[(size_t)j * Fdim + lane];
        }
        sacc[wid][lane] = acc;
        if (lane == 0) sden[wid] = den;
        __syncthreads();
        if (tid < 64) {
            float atot = sacc[0][tid] + sacc[1][tid] + sacc[2][tid] + sacc[3][tid];
            float dtot = sden[0] + sden[1] + sden[2] + sden[3];
            out_pre[(size_t)i * (H * Fdim) + hh * Fdim + tid] = atot / dtot;
        }
        __syncthreads();
    }
}

// ---------------------------------------------------------------------------
// Kernel 5: final row softmax over D=512 features, write bf16 or fp32 per flag.
// ---------------------------------------------------------------------------
__global__ __launch_bounds__(256) void row_softmax(const float* __restrict__ pre,
                                                   void* __restrict__ out_raw,
                                                   int D, const int* __restrict__ flags) {
    int is32 = flags[0];
    int row = blockIdx.x;
    const float* p = pre + (size_t)row * D;
    int tid = threadIdx.x, lane = tid & 63, wid = tid >> 6;
    __shared__ float sr[8];

    float v0 = p[tid], v1 = p[tid + 256];
    float m = fmaxf(v0, v1);
#pragma unroll
    for (int d = 32; d; d >>= 1) m = fmaxf(m, __shfl_down(m, d));
    if (lane == 0) sr[wid] = m;
    __syncthreads();
    if (tid == 0) sr[4] = fmaxf(fmaxf(sr[0], sr[1]), fmaxf(sr[2], sr[3]));
    __syncthreads();
    m = sr[4];
    float e0 = __expf(v0 - m), e1 = __expf(v1 - m);
    float s = e0 + e1;
#pragma unroll
    for (int d = 32; d; d >>= 1) s += __shfl_down(s, d);
    __syncthreads();
    if (lane == 0) sr[wid] = s;
    __syncthreads();
    if (tid == 0) sr[5] = sr[0] + sr[1] + sr[2] + sr[3];
    __syncthreads();
    s = sr[5];
    if (is32) {
        float* out = (float*)out_raw;
        out[(size_t)row * D + tid]       = e0 / s;
        out[(size_t)row * D + tid + 256] = e1 / s;
    } else {
        unsigned short* out = (unsigned short*)out_raw;
        out[(size_t)row * D + tid]       = f2bf(e0 / s);
        out[(size_t)row * D + tid + 256] = f2bf(e1 / s);
    }
}

// ---------------------------------------------------------------------------
extern "C" void kernel_launch(void* const* d_in, const int* in_sizes, int n_in,
                              void* d_out, int out_size, void* d_ws, size_t ws_size,
                              hipStream_t stream) {
    const int N = 4096, C = 512, Fdim = 64, H = 8;
    const int E = in_sizes[1] / 2;

    const void* x = d_in[0];
    const int*  ei = (const int*)d_in[1];
    const void* W = d_in[2];
    const void* a = d_in[3];

    char* ws = (char*)d_ws;
    float* h       = (float*)ws;                                    // 8 MB
    float* out_pre = (float*)(ws + (size_t)8 * 1024 * 1024);        // 8 MB
    float* s_src   = (float*)(ws + (size_t)16 * 1024 * 1024);       // 128 KB
    float* s_dst   = s_src + H * N;                                 // 128 KB
    unsigned long long* adj = (unsigned long long*)(ws + (size_t)17 * 1024 * 1024); // 2 MB
    int* flags = (int*)(ws + (size_t)19 * 1024 * 1024 + 512 * 1024);

    hipMemsetAsync(adj, 0, (size_t)N * (N / 8), stream);

    detect_types<<<1, 256, 0, stream>>>((const unsigned int*)x, ei, flags);
    build_adj<<<(E + N + 255) / 256, 256, 0, stream>>>(ei, E, N, adj, flags);
    gemm_h<<<dim3(N / BM, H), 256, 0, stream>>>(x, W, h, N, C, Fdim, flags);
    calc_s<<<(H * N) / 4, 256, 0, stream>>>(h, a, s_src, s_dst, N, Fdim, H, flags);
    attn<<<N, 256, 0, stream>>>(h, s_src, s_dst, adj, out_pre, N, Fdim, H);
    row_softmax<<<N, 256, 0, stream>>>(out_pre, d_out, H * Fdim, flags);
}

// Round 3
// 147.077 us; speedup vs baseline: 1.4193x; 1.4193x over previous
//
#include <hip/hip_runtime.h>

#define ALPHA 0.2f

__device__ __forceinline__ float bf2f(unsigned short u) {
    return __uint_as_float(((unsigned int)u) << 16);
}
__device__ __forceinline__ unsigned short f2bf(float f) {
    unsigned int x = __float_as_uint(f);
    unsigned int r = (x + 0x7fffu + ((x >> 16) & 1u)) >> 16;   // RNE
    return (unsigned short)r;
}

// ---------------------------------------------------------------------------
// Kernel 0: dtype detection (fp32 vs bf16 floats; int64 vs int32 edges).
// flags[0]=1 -> floats fp32.  flags[1]=1 -> edges int64.
// ---------------------------------------------------------------------------
__global__ __launch_bounds__(256) void detect_types(const unsigned int* __restrict__ xw,
                                                    const int* __restrict__ ei32,
                                                    int* __restrict__ flags) {
    __shared__ int cnt[2];
    if (threadIdx.x == 0) { cnt[0] = 0; cnt[1] = 0; }
    __syncthreads();
    int c0 = 0, c1 = 0;
    int t = threadIdx.x;
    for (int i = 0; i < 8; i++) {
        int k = t * 8 + i;
        unsigned int u = xw[k];
        unsigned int e = (u >> 7) & 0xffu;
        if (e >= 0x58u && e <= 0x90u) c0++;
        if (ei32[2 * k + 1] != 0) c1++;
    }
    atomicAdd(&cnt[0], c0);
    atomicAdd(&cnt[1], c1);
    __syncthreads();
    if (threadIdx.x == 0) {
        flags[0] = (cnt[0] < 1200) ? 1 : 0;
        flags[1] = (cnt[1] < 1000) ? 1 : 0;
    }
}

// ---------------------------------------------------------------------------
// Kernel 1: adjacency bitmask (dedup like the reference boolean adj).
// ---------------------------------------------------------------------------
__global__ __launch_bounds__(256) void build_adj(const int* __restrict__ ei, int E, int N,
                                                 unsigned long long* __restrict__ adj,
                                                 const int* __restrict__ flags) {
    int is64 = flags[1];
    int t = blockIdx.x * blockDim.x + threadIdx.x;
    int words = N >> 6;
    if (t < E) {
        int r = is64 ? ei[2 * t]       : ei[t];
        int c = is64 ? ei[2 * (E + t)] : ei[E + t];
        atomicOr(&adj[(size_t)r * words + (c >> 6)], 1ull << (c & 63));
    } else if (t < E + N) {
        int i = t - E;
        atomicOr(&adj[(size_t)i * words + (i >> 6)], 1ull << (i & 63));
    }
}

// ---------------------------------------------------------------------------
// Kernel 2: h2[n][head*64+f] = (x @ W[head])[n][f]   + fused s_src/s_dst.
// 64x64 tile per block, BK=32, 256 threads, 4x4 acc each.
// s_src2[n*8+h] = h[n,:] . a[h,0:64];  s_dst2[n*8+h] = h[n,:] . a[h,64:128]
// ---------------------------------------------------------------------------
#define BM 64
#define BN 64
#define BK 32
__global__ __launch_bounds__(256) void gemm_h(const void* __restrict__ x_raw,
                                              const void* __restrict__ W_raw,
                                              const void* __restrict__ a_raw,
                                              float* __restrict__ h2,
                                              float* __restrict__ s_src2,
                                              float* __restrict__ s_dst2,
                                              int N, int C, int Fdim, int H,
                                              const int* __restrict__ flags) {
    int is32 = flags[0];
    int head = blockIdx.y;
    int row0 = blockIdx.x * BM;

    __shared__ float sx[BK][BM + 4];
    __shared__ float sw[BK][BN + 4];

    int tid = threadIdx.x;
    int tx = tid & 15;
    int ty = tid >> 4;
    float acc[4][4] = {};

    for (int k0 = 0; k0 < C; k0 += BK) {
        if (is32) {
            const float* xf = (const float*)x_raw;
            const float* Wf = (const float*)W_raw + (size_t)head * C * Fdim;
#pragma unroll
            for (int i = 0; i < 2; i++) {
                int flat4 = tid + i * 256;           // 512 float4s for x tile
                int r  = flat4 >> 3;                 // 8 float4 per row of 32
                int k4 = flat4 & 7;
                float4 v = *(const float4*)(xf + (size_t)(row0 + r) * C + k0 + k4 * 4);
                sx[k4 * 4 + 0][r] = v.x; sx[k4 * 4 + 1][r] = v.y;
                sx[k4 * 4 + 2][r] = v.z; sx[k4 * 4 + 3][r] = v.w;
                int kk = flat4 >> 4;                 // 16 float4 per row of 64
                int f4 = flat4 & 15;
                *(float4*)&sw[kk][f4 * 4] = *(const float4*)(Wf + (size_t)(k0 + kk) * Fdim + f4 * 4);
            }
        } else {
            const unsigned short* xb = (const unsigned short*)x_raw;
            const unsigned short* Wb = (const unsigned short*)W_raw + (size_t)head * C * Fdim;
#pragma unroll
            for (int i = 0; i < 4; i++) {
                int flat2 = tid + i * 256;
                int r = flat2 >> 4, k2 = flat2 & 15;
                unsigned int u = *(const unsigned int*)(xb + (size_t)(row0 + r) * C + k0 + k2 * 2);
                sx[k2 * 2 + 0][r] = bf2f((unsigned short)(u & 0xffff));
                sx[k2 * 2 + 1][r] = bf2f((unsigned short)(u >> 16));
                int kk = flat2 >> 5, f2 = flat2 & 31;
                unsigned int v = *(const unsigned int*)(Wb + (size_t)(k0 + kk) * Fdim + f2 * 2);
                sw[kk][f2 * 2 + 0] = bf2f((unsigned short)(v & 0xffff));
                sw[kk][f2 * 2 + 1] = bf2f((unsigned short)(v >> 16));
            }
        }
        __syncthreads();
#pragma unroll
        for (int k = 0; k < BK; k++) {
            float a0 = sx[k][ty * 4 + 0], a1 = sx[k][ty * 4 + 1];
            float a2 = sx[k][ty * 4 + 2], a3 = sx[k][ty * 4 + 3];
            float b0 = sw[k][tx * 4 + 0], b1 = sw[k][tx * 4 + 1];
            float b2 = sw[k][tx * 4 + 2], b3 = sw[k][tx * 4 + 3];
            acc[0][0] += a0 * b0; acc[0][1] += a0 * b1; acc[0][2] += a0 * b2; acc[0][3] += a0 * b3;
            acc[1][0] += a1 * b0; acc[1][1] += a1 * b1; acc[1][2] += a1 * b2; acc[1][3] += a1 * b3;
            acc[2][0] += a2 * b0; acc[2][1] += a2 * b1; acc[2][2] += a2 * b2; acc[2][3] += a2 * b3;
            acc[3][0] += a3 * b0; acc[3][1] += a3 * b1; acc[3][2] += a3 * b2; acc[3][3] += a3 * b3;
        }
        __syncthreads();
    }

    // write h2 ([N][H*64] layout)
#pragma unroll
    for (int i = 0; i < 4; i++) {
        float4 v = make_float4(acc[i][0], acc[i][1], acc[i][2], acc[i][3]);
        *(float4*)(h2 + (size_t)(row0 + ty * 4 + i) * (H * Fdim) + head * Fdim + tx * 4) = v;
    }

    // fused s_src / s_dst: dot over the 64 cols (tx covers 4 each, reduce over tx)
    float asrc[4], adst[4];
    if (is32) {
        const float* af = (const float*)a_raw + head * 2 * Fdim;
#pragma unroll
        for (int j = 0; j < 4; j++) { asrc[j] = af[tx * 4 + j]; adst[j] = af[Fdim + tx * 4 + j]; }
    } else {
        const unsigned short* ab = (const unsigned short*)a_raw + head * 2 * Fdim;
#pragma unroll
        for (int j = 0; j < 4; j++) { asrc[j] = bf2f(ab[tx * 4 + j]); adst[j] = bf2f(ab[Fdim + tx * 4 + j]); }
    }
#pragma unroll
    for (int i = 0; i < 4; i++) {
        float s1 = acc[i][0] * asrc[0] + acc[i][1] * asrc[1] + acc[i][2] * asrc[2] + acc[i][3] * asrc[3];
        float s2 = acc[i][0] * adst[0] + acc[i][1] * adst[1] + acc[i][2] * adst[2] + acc[i][3] * adst[3];
#pragma unroll
        for (int d = 1; d < 16; d <<= 1) {
            s1 += __shfl_xor(s1, d);
            s2 += __shfl_xor(s2, d);
        }
        if (tx == 0) {
            int row = row0 + ty * 4 + i;
            s_src2[(size_t)row * H + head] = s1;
            s_dst2[(size_t)row * H + head] = s2;
        }
    }
}

// ---------------------------------------------------------------------------
// Kernel 3: attention + aggregation + final row softmax. Block per node i.
// All 8 heads processed together; h2 rows gathered as coalesced 2KB loads.
// ---------------------------------------------------------------------------
__global__ __launch_bounds__(256) void attn_out(const float* __restrict__ h2,
                                                const float* __restrict__ s_src2,
                                                const float* __restrict__ s_dst2,
                                                const unsigned long long* __restrict__ adj,
                                                void* __restrict__ out_raw,
                                                int N, int H,
                                                const int* __restrict__ flags) {
    __shared__ unsigned short nbrs[4096];
    __shared__ float w_lds[256 * 8];
    __shared__ float sss[8], smax[8], sden[8];
    __shared__ float sredw[4][8];
    __shared__ float sr[8];
    __shared__ int s_cnt;

    int i = blockIdx.x;
    int tid = threadIdx.x;
    int lane = tid & 63, wid = tid >> 6;

    // Phase 1: enumerate neighbors (wave 0), load s_src row (8 threads).
    if (tid < 64) {
        unsigned long long word = adj[(size_t)i * 64 + tid];
        int cnt = __popcll(word);
        int incl = cnt;
#pragma unroll
        for (int d = 1; d < 64; d <<= 1) {
            int v = __shfl_up(incl, d);
            if (tid >= d) incl += v;
        }
        int off = incl - cnt;
        unsigned long long w = word;
        int base = tid * 64;
        while (w) {
            int b = __ffsll((unsigned long long)w) - 1;
            nbrs[off++] = (unsigned short)(base + b);
            w &= w - 1;
        }
        if (tid == 63) s_cnt = incl;
    }
    if (tid >= 64 && tid < 72) sss[tid - 64] = s_src2[(size_t)i * H + (tid - 64)];
    __syncthreads();
    int cnt = s_cnt;

    // Phase 2: per-head max of s_dst over neighbors (threads grouped by tid&7).
    int hw = tid & 7;
    float mp = -1e30f;
    for (int t = tid; t < cnt * 8; t += 256)
        mp = fmaxf(mp, s_dst2[(size_t)nbrs[t >> 3] * H + hw]);
    mp = fmaxf(mp, __shfl_down(mp, 32));
    mp = fmaxf(mp, __shfl_down(mp, 16));
    mp = fmaxf(mp, __shfl_down(mp, 8));
    if (lane < 8) sredw[wid][lane] = mp;
    __syncthreads();
    if (tid < 8) {
        float m = fmaxf(fmaxf(sredw[0][tid], sredw[1][tid]), fmaxf(sredw[2][tid], sredw[3][tid]));
        float pre = sss[tid] + m;
        smax[tid] = pre > 0.f ? pre : ALPHA * pre;
    }
    __syncthreads();

    // Phase 3: chunked weights + h accumulation (all heads at once).
    int hh = tid >> 5;                     // head for the acc pass (2 feats each)
    float ssrc_w = sss[hw], maxe_w = smax[hw];
    float den = 0.f, ax = 0.f, ay = 0.f;
    for (int c0 = 0; c0 < cnt; c0 += 256) {
        int csz = min(256, cnt - c0);
        __syncthreads();                   // w_lds reuse guard
        for (int t = tid; t < csz * 8; t += 256) {
            int j = nbrs[c0 + (t >> 3)];
            float e = ssrc_w + s_dst2[(size_t)j * H + hw];
            e = e > 0.f ? e : ALPHA * e;
            float w = __expf(e - maxe_w);
            w_lds[t] = w;
            den += w;
        }
        __syncthreads();
#pragma unroll 2
        for (int jj = 0; jj < csz; jj++) {
            int j = nbrs[c0 + jj];
            float2 v = *(const float2*)(h2 + (size_t)j * 512 + tid * 2);
            float w = w_lds[jj * 8 + hh];
            ax += w * v.x;
            ay += w * v.y;
        }
    }

    // Phase 4: reduce den per head.
    den += __shfl_down(den, 32);
    den += __shfl_down(den, 16);
    den += __shfl_down(den, 8);
    if (lane < 8) sredw[wid][lane] = den;
    __syncthreads();
    if (tid < 8) sden[tid] = sredw[0][tid] + sredw[1][tid] + sredw[2][tid] + sredw[3][tid];
    __syncthreads();
    float dtot = sden[hh];
    float o0 = ax / dtot, o1 = ay / dtot;

    // Phase 5: fused row softmax over 512 (2 per thread).
    float m2 = fmaxf(o0, o1);
#pragma unroll
    for (int d = 32; d; d >>= 1) m2 = fmaxf(m2, __shfl_down(m2, d));
    if (lane == 0) sr[wid] = m2;
    __syncthreads();
    float m = fmaxf(fmaxf(sr[0], sr[1]), fmaxf(sr[2], sr[3]));
    float e0 = __expf(o0 - m), e1 = __expf(o1 - m);
    float s = e0 + e1;
#pragma unroll
    for (int d = 32; d; d >>= 1) s += __shfl_down(s, d);
    __syncthreads();
    if (lane == 0) sr[wid + 4] = s;
    __syncthreads();
    s = sr[4] + sr[5] + sr[6] + sr[7];

    if (flags[0]) {
        float2* out = (float2*)out_raw;
        out[(size_t)i * 256 + tid] = make_float2(e0 / s, e1 / s);
    } else {
        unsigned int* out = (unsigned int*)out_raw;
        out[(size_t)i * 256 + tid] = (unsigned int)f2bf(e0 / s) | ((unsigned int)f2bf(e1 / s) << 16);
    }
}

// ---------------------------------------------------------------------------
extern "C" void kernel_launch(void* const* d_in, const int* in_sizes, int n_in,
                              void* d_out, int out_size, void* d_ws, size_t ws_size,
                              hipStream_t stream) {
    const int N = 4096, C = 512, Fdim = 64, H = 8;
    const int E = in_sizes[1] / 2;

    const void* x = d_in[0];
    const int*  ei = (const int*)d_in[1];
    const void* W = d_in[2];
    const void* a = d_in[3];

    char* ws = (char*)d_ws;
    float* h2     = (float*)ws;                                      // 8 MB
    float* s_src2 = (float*)(ws + (size_t)8 * 1024 * 1024);          // 128 KB
    float* s_dst2 = s_src2 + (size_t)N * H;                          // 128 KB
    unsigned long long* adj = (unsigned long long*)(ws + (size_t)9 * 1024 * 1024); // 2 MB
    int* flags = (int*)(ws + (size_t)11 * 1024 * 1024 + 512 * 1024);

    hipMemsetAsync(adj, 0, (size_t)N * (N / 8), stream);

    detect_types<<<1, 256, 0, stream>>>((const unsigned int*)x, ei, flags);
    build_adj<<<(E + N + 255) / 256, 256, 0, stream>>>(ei, E, N, adj, flags);
    gemm_h<<<dim3(N / BM, H), 256, 0, stream>>>(x, W, a, h2, s_src2, s_dst2, N, C, Fdim, H, flags);
    attn_out<<<N, 256, 0, stream>>>(h2, s_src2, s_dst2, adj, d_out, N, H, flags);
}

// Round 4
// 134.045 us; speedup vs baseline: 1.5573x; 1.0972x over previous
//
#include <hip/hip_runtime.h>

#define ALPHA 0.2f

typedef __attribute__((ext_vector_type(8))) short short8;
typedef __attribute__((ext_vector_type(8))) unsigned short ushort8;
typedef __attribute__((ext_vector_type(4))) float f32x4;

__device__ __forceinline__ float bf2f(unsigned short u) {
    return __uint_as_float(((unsigned int)u) << 16);
}
__device__ __forceinline__ unsigned short f2bf(float f) {
    unsigned int x = __float_as_uint(f);
    unsigned int r = (x + 0x7fffu + ((x >> 16) & 1u)) >> 16;   // RNE
    return (unsigned short)r;
}

// ---------------------------------------------------------------------------
// Kernel 0: dtype detection. flags[0]=1 -> floats fp32. flags[1]=1 -> edges int64.
// ---------------------------------------------------------------------------
__global__ __launch_bounds__(256) void detect_types(const unsigned int* __restrict__ xw,
                                                    const int* __restrict__ ei32,
                                                    int* __restrict__ flags) {
    __shared__ int cnt[2];
    if (threadIdx.x == 0) { cnt[0] = 0; cnt[1] = 0; }
    __syncthreads();
    int c0 = 0, c1 = 0;
    int t = threadIdx.x;
    for (int i = 0; i < 8; i++) {
        int k = t * 8 + i;
        unsigned int u = xw[k];
        unsigned int e = (u >> 7) & 0xffu;
        if (e >= 0x58u && e <= 0x90u) c0++;
        if (ei32[2 * k + 1] != 0) c1++;
    }
    atomicAdd(&cnt[0], c0);
    atomicAdd(&cnt[1], c1);
    __syncthreads();
    if (threadIdx.x == 0) {
        flags[0] = (cnt[0] < 1200) ? 1 : 0;
        flags[1] = (cnt[1] < 1000) ? 1 : 0;
    }
}

// ---------------------------------------------------------------------------
// Kernel 1: split fp32 -> bf16 hi/lo planes. x planes [N][C]; W planes
// TRANSPOSED to [H][F][C] so GEMM LDS staging is row-contiguous.
// ---------------------------------------------------------------------------
__global__ __launch_bounds__(256) void split_bf16(const void* __restrict__ x_raw,
                                                  const void* __restrict__ W_raw,
                                                  unsigned short* __restrict__ x_hi,
                                                  unsigned short* __restrict__ x_lo,
                                                  unsigned short* __restrict__ wt_hi,
                                                  unsigned short* __restrict__ wt_lo,
                                                  const int* __restrict__ flags) {
    int is32 = flags[0];
    int bid = blockIdx.x, tid = threadIdx.x;
    if (bid < 1024) {                       // x: 4096*512 = 2M elems, 8/thread
        size_t base = ((size_t)bid * 256 + tid) * 8;
        ushort8 h8, l8;
        if (is32) {
            const float* xf = (const float*)x_raw;
            float4 v0 = *(const float4*)(xf + base);
            float4 v1 = *(const float4*)(xf + base + 4);
            float v[8] = {v0.x, v0.y, v0.z, v0.w, v1.x, v1.y, v1.z, v1.w};
#pragma unroll
            for (int j = 0; j < 8; j++) {
                unsigned short hi = f2bf(v[j]);
                h8[j] = hi;
                l8[j] = f2bf(v[j] - bf2f(hi));
            }
        } else {
            const ushort8* xb = (const ushort8*)x_raw;
            h8 = xb[base / 8];
            l8 = (ushort8)0;
        }
        *(ushort8*)(x_hi + base) = h8;
        *(ushort8*)(x_lo + base) = l8;
    } else {                                // W: 8*512*64 = 262144 elems
        size_t u = ((size_t)(bid - 1024) * 256 + tid) * 8;
#pragma unroll
        for (int j = 0; j < 8; j++) {
            size_t e = u + j;
            int head = (int)(e >> 15);
            int c = (int)((e >> 6) & 511);
            int f = (int)(e & 63);
            unsigned short hi, lo;
            if (is32) {
                float v = ((const float*)W_raw)[e];
                hi = f2bf(v);
                lo = f2bf(v - bf2f(hi));
            } else {
                hi = ((const unsigned short*)W_raw)[e];
                lo = 0;
            }
            size_t o = (size_t)head * 32768 + (size_t)f * 512 + c;
            wt_hi[o] = hi;
            wt_lo[o] = lo;
        }
    }
}

// ---------------------------------------------------------------------------
// Kernel 2: adjacency bitmask (dedup like the reference boolean adj).
// ---------------------------------------------------------------------------
__global__ __launch_bounds__(256) void build_adj(const int* __restrict__ ei, int E, int N,
                                                 unsigned long long* __restrict__ adj,
                                                 const int* __restrict__ flags) {
    int is64 = flags[1];
    int t = blockIdx.x * blockDim.x + threadIdx.x;
    int words = N >> 6;
    if (t < E) {
        int r = is64 ? ei[2 * t]       : ei[t];
        int c = is64 ? ei[2 * (E + t)] : ei[E + t];
        atomicOr(&adj[(size_t)r * words + (c >> 6)], 1ull << (c & 63));
    } else if (t < E + N) {
        int i = t - E;
        atomicOr(&adj[(size_t)i * words + (i >> 6)], 1ull << (i & 63));
    }
}

// ---------------------------------------------------------------------------
// Kernel 3: MFMA GEMM (bf16x3): h2[n][head*64+f] = x @ W[head], + fused s_src/s_dst.
// Block: 64 rows x 64 cols (one head). 4 waves, each 16 rows x 64 cols
// = 4 tiles of mfma_f32_16x16x32_bf16. K' = 3 planes x 512.
// LDS rows padded to 40 ushorts (80 B) -> frag ds_read_b128 2-way max (free).
// ---------------------------------------------------------------------------
#define LROW 40
__global__ __launch_bounds__(256) void gemm_mfma(const unsigned short* __restrict__ xh,
                                                 const unsigned short* __restrict__ xl,
                                                 const unsigned short* __restrict__ wth,
                                                 const unsigned short* __restrict__ wtl,
                                                 const void* __restrict__ a_raw,
                                                 float* __restrict__ h2,
                                                 float* __restrict__ s_src2,
                                                 float* __restrict__ s_dst2,
                                                 const int* __restrict__ flags) {
    __shared__ unsigned short sA[64 * LROW];
    __shared__ unsigned short sB[64 * LROW];

    int head = blockIdx.y;
    int row0 = blockIdx.x * 64;
    int tid = threadIdx.x;
    int w = tid >> 6, lane = tid & 63;
    int m = lane & 15, quad = lane >> 4;
    int sr = tid >> 2, sc = tid & 3;            // staging: row 0..63, 16B-chunk 0..3

    const unsigned short* Ap[3] = {xh, xl, xh};
    const unsigned short* Bp[3] = {wth, wth, wtl};
    size_t baseA = (size_t)(row0 + sr) * 512 + sc * 8;
    size_t baseB = (size_t)head * 32768 + (size_t)sr * 512 + sc * 8;

    f32x4 acc[4] = {f32x4{0.f, 0.f, 0.f, 0.f}, f32x4{0.f, 0.f, 0.f, 0.f},
                    f32x4{0.f, 0.f, 0.f, 0.f}, f32x4{0.f, 0.f, 0.f, 0.f}};

    int ldsw = sr * LROW + sc * 8;
    int ldsA = (w * 16 + m) * LROW + quad * 8;

    ushort8 ra = *(const ushort8*)(Ap[0] + baseA);
    ushort8 rb = *(const ushort8*)(Bp[0] + baseB);

    for (int i = 0; i < 48; i++) {
        __syncthreads();
        *(ushort8*)&sA[ldsw] = ra;
        *(ushort8*)&sB[ldsw] = rb;
        __syncthreads();
        int inx = (i + 1 < 48) ? i + 1 : 47;
        int pn = inx >> 4, kn = (inx & 15) * 32;
        ra = *(const ushort8*)(Ap[pn] + baseA + kn);
        rb = *(const ushort8*)(Bp[pn] + baseB + kn);

        short8 af = *(const short8*)&sA[ldsA];
#pragma unroll
        for (int t = 0; t < 4; t++) {
            short8 bf = *(const short8*)&sB[(t * 16 + m) * LROW + quad * 8];
            acc[t] = __builtin_amdgcn_mfma_f32_16x16x32_bf16(af, bf, acc[t], 0, 0, 0);
        }
    }

    // epilogue: write h2 ([N][512]); D layout: col = lane&15, row = quad*4+reg
#pragma unroll
    for (int t = 0; t < 4; t++)
#pragma unroll
        for (int reg = 0; reg < 4; reg++) {
            int r = row0 + w * 16 + quad * 4 + reg;
            h2[(size_t)r * 512 + head * 64 + t * 16 + m] = acc[t][reg];
        }

    // fused s_src/s_dst
    float as[4], ad[4];
    if (flags[0]) {
        const float* af32 = (const float*)a_raw + head * 128;
#pragma unroll
        for (int t = 0; t < 4; t++) {
            as[t] = af32[t * 16 + m];
            ad[t] = af32[64 + t * 16 + m];
        }
    } else {
        const unsigned short* ab = (const unsigned short*)a_raw + head * 128;
#pragma unroll
        for (int t = 0; t < 4; t++) {
            as[t] = bf2f(ab[t * 16 + m]);
            ad[t] = bf2f(ab[64 + t * 16 + m]);
        }
    }
#pragma unroll
    for (int reg = 0; reg < 4; reg++) {
        float s1 = as[0] * acc[0][reg] + as[1] * acc[1][reg] + as[2] * acc[2][reg] + as[3] * acc[3][reg];
        float s2 = ad[0] * acc[0][reg] + ad[1] * acc[1][reg] + ad[2] * acc[2][reg] + ad[3] * acc[3][reg];
#pragma unroll
        for (int d = 1; d < 16; d <<= 1) {
            s1 += __shfl_xor(s1, d);
            s2 += __shfl_xor(s2, d);
        }
        if (m == 0) {
            int r = row0 + w * 16 + quad * 4 + reg;
            s_src2[(size_t)r * 8 + head] = s1;
            s_dst2[(size_t)r * 8 + head] = s2;
        }
    }
}

// ---------------------------------------------------------------------------
// Kernel 4: attention + aggregation + final row softmax. Block per node i.
// ---------------------------------------------------------------------------
__global__ __launch_bounds__(256) void attn_out(const float* __restrict__ h2,
                                                const float* __restrict__ s_src2,
                                                const float* __restrict__ s_dst2,
                                                const unsigned long long* __restrict__ adj,
                                                void* __restrict__ out_raw,
                                                int N, int H,
                                                const int* __restrict__ flags) {
    __shared__ unsigned short nbrs[4096];
    __shared__ float w_lds[256 * 8];
    __shared__ float sss[8], smax[8], sden[8];
    __shared__ float sredw[4][8];
    __shared__ float sr[8];
    __shared__ int s_cnt;

    int i = blockIdx.x;
    int tid = threadIdx.x;
    int lane = tid & 63, wid = tid >> 6;

    if (tid < 64) {
        unsigned long long word = adj[(size_t)i * 64 + tid];
        int cnt = __popcll(word);
        int incl = cnt;
#pragma unroll
        for (int d = 1; d < 64; d <<= 1) {
            int v = __shfl_up(incl, d);
            if (tid >= d) incl += v;
        }
        int off = incl - cnt;
        unsigned long long w = word;
        int base = tid * 64;
        while (w) {
            int b = __ffsll((unsigned long long)w) - 1;
            nbrs[off++] = (unsigned short)(base + b);
            w &= w - 1;
        }
        if (tid == 63) s_cnt = incl;
    }
    if (tid >= 64 && tid < 72) sss[tid - 64] = s_src2[(size_t)i * H + (tid - 64)];
    __syncthreads();
    int cnt = s_cnt;

    int hw = tid & 7;
    float mp = -1e30f;
    for (int t = tid; t < cnt * 8; t += 256)
        mp = fmaxf(mp, s_dst2[(size_t)nbrs[t >> 3] * H + hw]);
    mp = fmaxf(mp, __shfl_down(mp, 32));
    mp = fmaxf(mp, __shfl_down(mp, 16));
    mp = fmaxf(mp, __shfl_down(mp, 8));
    if (lane < 8) sredw[wid][lane] = mp;
    __syncthreads();
    if (tid < 8) {
        float m = fmaxf(fmaxf(sredw[0][tid], sredw[1][tid]), fmaxf(sredw[2][tid], sredw[3][tid]));
        float pre = sss[tid] + m;
        smax[tid] = pre > 0.f ? pre : ALPHA * pre;
    }
    __syncthreads();

    int hh = tid >> 5;
    float ssrc_w = sss[hw], maxe_w = smax[hw];
    float den = 0.f, ax = 0.f, ay = 0.f;
    for (int c0 = 0; c0 < cnt; c0 += 256) {
        int csz = min(256, cnt - c0);
        __syncthreads();
        for (int t = tid; t < csz * 8; t += 256) {
            int j = nbrs[c0 + (t >> 3)];
            float e = ssrc_w + s_dst2[(size_t)j * H + hw];
            e = e > 0.f ? e : ALPHA * e;
            float w = __expf(e - maxe_w);
            w_lds[t] = w;
            den += w;
        }
        __syncthreads();
#pragma unroll 2
        for (int jj = 0; jj < csz; jj++) {
            int j = nbrs[c0 + jj];
            float2 v = *(const float2*)(h2 + (size_t)j * 512 + tid * 2);
            float w = w_lds[jj * 8 + hh];
            ax += w * v.x;
            ay += w * v.y;
        }
    }

    den += __shfl_down(den, 32);
    den += __shfl_down(den, 16);
    den += __shfl_down(den, 8);
    if (lane < 8) sredw[wid][lane] = den;
    __syncthreads();
    if (tid < 8) sden[tid] = sredw[0][tid] + sredw[1][tid] + sredw[2][tid] + sredw[3][tid];
    __syncthreads();
    float dtot = sden[hh];
    float o0 = ax / dtot, o1 = ay / dtot;

    float m2 = fmaxf(o0, o1);
#pragma unroll
    for (int d = 32; d; d >>= 1) m2 = fmaxf(m2, __shfl_down(m2, d));
    if (lane == 0) sr[wid] = m2;
    __syncthreads();
    float m = fmaxf(fmaxf(sr[0], sr[1]), fmaxf(sr[2], sr[3]));
    float e0 = __expf(o0 - m), e1 = __expf(o1 - m);
    float s = e0 + e1;
#pragma unroll
    for (int d = 32; d; d >>= 1) s += __shfl_down(s, d);
    __syncthreads();
    if (lane == 0) sr[wid + 4] = s;
    __syncthreads();
    s = sr[4] + sr[5] + sr[6] + sr[7];

    if (flags[0]) {
        float2* out = (float2*)out_raw;
        out[(size_t)i * 256 + tid] = make_float2(e0 / s, e1 / s);
    } else {
        unsigned int* out = (unsigned int*)out_raw;
        out[(size_t)i * 256 + tid] = (unsigned int)f2bf(e0 / s) | ((unsigned int)f2bf(e1 / s) << 16);
    }
}

// ---------------------------------------------------------------------------
extern "C" void kernel_launch(void* const* d_in, const int* in_sizes, int n_in,
                              void* d_out, int out_size, void* d_ws, size_t ws_size,
                              hipStream_t stream) {
    const int N = 4096, H = 8;
    const int E = in_sizes[1] / 2;

    const void* x = d_in[0];
    const int*  ei = (const int*)d_in[1];
    const void* W = d_in[2];
    const void* a = d_in[3];

    char* ws = (char*)d_ws;
    float* h2     = (float*)ws;                                          // 8 MB
    float* s_src2 = (float*)(ws + (size_t)8 * 1024 * 1024);              // 128 KB
    float* s_dst2 = s_src2 + (size_t)N * H;                              // 128 KB
    unsigned long long* adj = (unsigned long long*)(ws + (size_t)9 * 1024 * 1024); // 2 MB
    int* flags = (int*)(ws + (size_t)11 * 1024 * 1024 + 512 * 1024);
    unsigned short* x_hi  = (unsigned short*)(ws + (size_t)12 * 1024 * 1024);      // 4 MB
    unsigned short* x_lo  = (unsigned short*)(ws + (size_t)16 * 1024 * 1024);      // 4 MB
    unsigned short* wt_hi = (unsigned short*)(ws + (size_t)20 * 1024 * 1024);      // 512 KB
    unsigned short* wt_lo = (unsigned short*)(ws + (size_t)20 * 1024 * 1024 + 512 * 1024);

    hipMemsetAsync(adj, 0, (size_t)N * (N / 8), stream);

    detect_types<<<1, 256, 0, stream>>>((const unsigned int*)x, ei, flags);
    split_bf16<<<1152, 256, 0, stream>>>(x, W, x_hi, x_lo, wt_hi, wt_lo, flags);
    build_adj<<<(E + N + 255) / 256, 256, 0, stream>>>(ei, E, N, adj, flags);
    gemm_mfma<<<dim3(N / 64, H), 256, 0, stream>>>(x_hi, x_lo, wt_hi, wt_lo, a,
                                                   h2, s_src2, s_dst2, flags);
    attn_out<<<N, 256, 0, stream>>>(h2, s_src2, s_dst2, adj, d_out, N, H, flags);
}